// Round 13
// baseline (290.825 us; speedup 1.0000x reference)
//
#include <hip/hip_runtime.h>
#include <hip/hip_fp16.h>

#define N_NODES 50000
#define MPAD    50048            // 782 * 64
#define N_EDGES 500000
#define F_IN    112
#define K1P     128              // F_IN padded (halves per x16/aX row)
#define F1      336
#define K2P     352              // F1 padded to 32-multiple
#define F2      168
#define NGRAPH  256
#define SCAN_CHUNK 1024
#define SCAN_BLOCKS ((N_NODES + SCAN_CHUNK - 1) / SCAN_CHUNK)   // 49

typedef __attribute__((ext_vector_type(8))) _Float16 f16x8;
typedef __attribute__((ext_vector_type(4))) float f32x4;
typedef unsigned short ushort_t;

__device__ __forceinline__ ushort_t f16_bits(float x) {
    __half h = __float2half_rn(x);
    return *(ushort_t*)&h;
}

// ---------------- small utility kernels ----------------
__global__ void k_zero_int(int* p, int n) {
    int i = blockIdx.x * blockDim.x + threadIdx.x;
    if (i < n) p[i] = 0;
}

// ---------------- fused prep: cvtX(pad128) | count_deg | cvtW1 | cvtW2 | ranges ----------------
#define CVX_BLOCKS  ((N_NODES * 32) / 256)                 // 6250 (uint2 per thread)
#define CNT_BLOCKS  ((N_EDGES / 2 + 255) / 256)            // 977
#define CVW1_BLOCKS ((384 * K1P + 255) / 256)              // 192
#define CVW2_BLOCKS ((192 * K2P + 255) / 256)              // 264
#define RNG_BLOCKS  ((N_NODES + 255) / 256)                // 196
#define PREP_BLOCKS (CVX_BLOCKS + CNT_BLOCKS + CVW1_BLOCKS + CVW2_BLOCKS + RNG_BLOCKS)

__global__ __launch_bounds__(256) void k_prep(const float* __restrict__ x,
                                              const int* __restrict__ dst,
                                              const float* __restrict__ W1,
                                              const float* __restrict__ W2,
                                              const int* __restrict__ batch,
                                              ushort_t* __restrict__ x16,   // [N][128]
                                              int* __restrict__ dcount,
                                              ushort_t* __restrict__ w1t,   // [384][128]
                                              ushort_t* __restrict__ w2t,   // [192][352]
                                              int* __restrict__ r0, int* __restrict__ r1) {
    int bid = blockIdx.x;
    int t = threadIdx.x;
    if (bid < CVX_BLOCKS) {                       // X fp32 -> fp16, padded rows of 128 halves
        int i = bid * 256 + t;                    // uint2 (4 halves) index; i = v*32 + c
        int v = i >> 5, c = i & 31;
        uint2 u = {0, 0};
        if (c < 28) {
            float4 f = *(const float4*)&x[(long)v * F_IN + c * 4];
            __half2 h0 = __floats2half2_rn(f.x, f.y);
            __half2 h1 = __floats2half2_rn(f.z, f.w);
            u.x = *(unsigned*)&h0; u.y = *(unsigned*)&h1;
        }
        ((uint2*)x16)[i] = u;
        return;
    }
    bid -= CVX_BLOCKS;
    if (bid < CNT_BLOCKS) {                       // degree count, 2 edges/thread
        int i = bid * 256 + t;
        if (i < N_EDGES / 2) {
            int2 d = ((const int2*)dst)[i];
            atomicAdd(&dcount[d.x], 1);
            atomicAdd(&dcount[d.y], 1);
        }
        return;
    }
    bid -= CNT_BLOCKS;
    if (bid < CVW1_BLOCKS) {                      // W1[K,N] -> w1t[n][k]
        int idx = bid * 256 + t;
        if (idx < 384 * K1P) {
            int n = idx / K1P, k = idx % K1P;
            float v = (n < F1 && k < F_IN) ? W1[k * F1 + n] : 0.0f;
            w1t[idx] = f16_bits(v);
        }
        return;
    }
    bid -= CVW1_BLOCKS;
    if (bid < CVW2_BLOCKS) {                      // W2[K,N] -> w2t[n][k]
        int idx = bid * 256 + t;
        if (idx < 192 * K2P) {
            int n = idx / K2P, k = idx % K2P;
            float v = (n < F2 && k < F1) ? W2[k * F2 + n] : 0.0f;
            w2t[idx] = f16_bits(v);
        }
        return;
    }
    bid -= CVW2_BLOCKS;
    {                                             // per-graph ranges (batch sorted)
        int v = bid * 256 + t;
        if (v >= N_NODES) return;
        int b = batch[v];
        if (v == 0 || batch[v - 1] != b) r0[b] = v;
        if (v == N_NODES - 1 || batch[v + 1] != b) r1[b] = v + 1;
    }
}

// ---------------- scan pass 1 (dinv fused) ----------------
__global__ __launch_bounds__(SCAN_CHUNK) void k_scan1(const int* __restrict__ dcount,
                                                      int* __restrict__ off,
                                                      int* __restrict__ partials,
                                                      float* __restrict__ dinv, int n) {
    __shared__ int s[SCAN_CHUNK];
    int t = threadIdx.x;
    int i = blockIdx.x * SCAN_CHUNK + t;
    int val = (i < n) ? dcount[i] : 0;
    s[t] = val;
    __syncthreads();
    for (int d = 1; d < SCAN_CHUNK; d <<= 1) {
        int x = (t >= d) ? s[t - d] : 0;
        __syncthreads();
        s[t] += x;
        __syncthreads();
    }
    if (i < n) {
        off[i] = s[t] - val;
        dinv[i] = rsqrtf((float)val + 1.0f);      // +1 self-loop
    }
    if (t == SCAN_CHUNK - 1) partials[blockIdx.x] = s[t];
}
// scan pass 2+3 merged
__global__ __launch_bounds__(SCAN_CHUNK) void k_scan3(int* __restrict__ off,
                                                      const int* __restrict__ partials, int n) {
    __shared__ int tmp[SCAN_BLOCKS];
    __shared__ int pref[SCAN_BLOCKS];
    int t = threadIdx.x;
    if (t < SCAN_BLOCKS) tmp[t] = partials[t];
    __syncthreads();
    if (t == 0) {
        int run = 0;
        for (int j = 0; j < SCAN_BLOCKS; ++j) { pref[j] = run; run += tmp[j]; }
    }
    __syncthreads();
    int i = blockIdx.x * SCAN_CHUNK + t;
    if (i < n) off[i] += pref[blockIdx.x];
    if (i == n) off[i] = N_EDGES;
}

// ---------------- scatter edges into dst-sorted CSR, 2 edges/thread ----------------
__global__ void k_scatter(const int* __restrict__ src, const int* __restrict__ dst,
                          const int* __restrict__ off, int* __restrict__ cur,
                          const float* __restrict__ dinv,
                          unsigned long long* __restrict__ csr, int e2) {
    int i = blockIdx.x * blockDim.x + threadIdx.x;
    if (i >= e2) return;
    int2 s2 = ((const int2*)src)[i];
    int2 d2 = ((const int2*)dst)[i];
    {
        int pos = atomicAdd(&cur[d2.x], 1);
        unsigned coef = __float_as_uint(dinv[s2.x] * dinv[d2.x]);
        unsigned long long rec = (unsigned)s2.x | ((unsigned long long)coef << 32);
        __builtin_nontemporal_store(rec, &csr[off[d2.x] + pos]);
    }
    {
        int pos = atomicAdd(&cur[d2.y], 1);
        unsigned coef = __float_as_uint(dinv[s2.y] * dinv[d2.y]);
        unsigned long long rec = (unsigned)s2.y | ((unsigned long long)coef << 32);
        __builtin_nontemporal_store(rec, &csr[off[d2.y] + pos]);
    }
}

// ---------------- agg layer 1: 2 nodes/wave, depth-8, CSR double-buffered ----------------
__global__ __launch_bounds__(256) void k_agg1(const ushort_t* __restrict__ X16,
                                              const int* __restrict__ off,
                                              const unsigned long long* __restrict__ csr,
                                              const float* __restrict__ dinv,
                                              ushort_t* __restrict__ aX) {
    int w = (blockIdx.x * 256 + threadIdx.x) >> 6;
    int lane = threadIdx.x & 63;
    if (w >= N_NODES / 2) return;
    const int g = lane >> 5, sl = lane & 31;
    const int v = 2 * w + g;
    int o0A = off[2 * w], oM = off[2 * w + 1], o1B = off[2 * w + 2];
    int o0 = g ? oM : o0A;
    int n  = g ? (o1B - oM) : (oM - o0A);
    int nmax = max(oM - o0A, o1B - oM);
    float di = dinv[v];
    float s2 = di * di;
    // all 32 lanes live: pad cols are zero in X16
    uint2 us = *(const uint2*)(X16 + (long)v * K1P + sl * 4);
    float2 sf0 = __half22float2(*(__half2*)&us.x);
    float2 sf1 = __half22float2(*(__half2*)&us.y);
    float4 acc = {sf0.x * s2, sf0.y * s2, sf1.x * s2, sf1.y * s2};
    int nm1 = max(n - 1, 0);
    unsigned long long e[8];
    #pragma unroll
    for (int j = 0; j < 8; ++j)
        e[j] = csr[min(o0 + min(j, nm1), N_EDGES - 1)];   // prime
    for (int b = 0; b < nmax; b += 8) {
        unsigned long long en[8];
        #pragma unroll
        for (int j = 0; j < 8; ++j)                        // prefetch next iter's records
            en[j] = csr[min(o0 + min(b + 8 + j, nm1), N_EDGES - 1)];
        uint2 u[8];
        #pragma unroll
        for (int j = 0; j < 8; ++j)
            u[j] = *(const uint2*)(X16 + (long)(unsigned)(e[j] & 0xFFFFFFFFu) * K1P + sl * 4);
        #pragma unroll
        for (int j = 0; j < 8; ++j) {
            float c = ((b + j) < n) ? __uint_as_float((unsigned)(e[j] >> 32)) : 0.0f;
            float2 f0 = __half22float2(*(__half2*)&u[j].x);
            float2 f1 = __half22float2(*(__half2*)&u[j].y);
            acc.x += c * f0.x; acc.y += c * f0.y; acc.z += c * f1.x; acc.w += c * f1.y;
        }
        #pragma unroll
        for (int j = 0; j < 8; ++j) e[j] = en[j];
    }
    __half2 h0 = __floats2half2_rn(acc.x, acc.y);
    __half2 h1 = __floats2half2_rn(acc.z, acc.w);
    uint2 o; o.x = *(unsigned*)&h0; o.y = *(unsigned*)&h1;
    *(uint2*)(aX + (long)v * K1P + sl * 4) = o;
}

// ---------------- fused GEMM1+GEMM2: T2 = (relu(aX@W1t^T + b1)) @ W2t^T ----------------
// One 64-row block: phase1 -> H1 tile (64x352 fp16) in LDS -> phase2 -> T2 (width 168, unpadded).
__global__ __launch_bounds__(256) void k_gemm_fused(
        const ushort_t* __restrict__ aX,    // [MPAD][128]
        const ushort_t* __restrict__ w1t,   // [384][128] rows 0..351 used
        const float* __restrict__ b1,       // [336]
        const ushort_t* __restrict__ w2t,   // [192][352]
        ushort_t* __restrict__ T2) {        // [MPAD][168]
    __shared__ ushort_t As[64][40];
    __shared__ ushort_t Bs[352][40];
    __shared__ ushort_t H1s[64][360];
    const int tid = threadIdx.x;
    const int row0 = blockIdx.x * 64;
    const int w = tid >> 6, l = tid & 63;
    const int wm = w >> 1, wn = w & 1;
    const int lm = l & 15, lq = l >> 4;

    // ---- phase 1 ----
    f32x4 acc1[2][11];
    #pragma unroll
    for (int i = 0; i < 2; ++i)
        #pragma unroll
        for (int j = 0; j < 11; ++j) acc1[i][j] = (f32x4){0.f, 0.f, 0.f, 0.f};

    for (int k0 = 0; k0 < K1P; k0 += 32) {
        {   // stage As
            int r = tid >> 2, s = (tid & 3) * 8;
            *(int4*)&As[r][s] = *(const int4*)&aX[(long)(row0 + r) * K1P + k0 + s];
        }
        #pragma unroll
        for (int it = 0; it < 6; ++it) {   // stage Bs: 352 rows x 4 segs = 1408
            int f = tid + it * 256;
            if (f < 1408) {
                int r = f >> 2, s = (f & 3) * 8;
                *(int4*)&Bs[r][s] = *(const int4*)&w1t[(long)r * K1P + k0 + s];
            }
        }
        __syncthreads();
        f16x8 af0 = *(const f16x8*)&As[wm * 32 + lm][lq * 8];
        f16x8 af1 = *(const f16x8*)&As[wm * 32 + 16 + lm][lq * 8];
        #pragma unroll
        for (int ns = 0; ns < 11; ++ns) {
            f16x8 bf = *(const f16x8*)&Bs[wn * 176 + ns * 16 + lm][lq * 8];
            acc1[0][ns] = __builtin_amdgcn_mfma_f32_16x16x32_f16(af0, bf, acc1[0][ns], 0, 0, 0);
            acc1[1][ns] = __builtin_amdgcn_mfma_f32_16x16x32_f16(af1, bf, acc1[1][ns], 0, 0, 0);
        }
        __syncthreads();
    }
    // write H1 tile to LDS with bias+relu (C/D layout: col=lm, row=lq*4+i)
    #pragma unroll
    for (int ms = 0; ms < 2; ++ms)
        #pragma unroll
        for (int ns = 0; ns < 11; ++ns) {
            int col = wn * 176 + ns * 16 + lm;
            float bb = (col < F1) ? b1[col] : 0.0f;
            #pragma unroll
            for (int i = 0; i < 4; ++i) {
                int r = wm * 32 + ms * 16 + lq * 4 + i;
                H1s[r][col] = f16_bits(fmaxf(acc1[ms][ns][i] + bb, 0.0f));
            }
        }
    __syncthreads();

    // ---- phase 2 ----
    f32x4 acc2[2][6];
    #pragma unroll
    for (int i = 0; i < 2; ++i)
        #pragma unroll
        for (int j = 0; j < 6; ++j) acc2[i][j] = (f32x4){0.f, 0.f, 0.f, 0.f};

    for (int k0 = 0; k0 < K2P; k0 += 32) {
        #pragma unroll
        for (int it = 0; it < 3; ++it) {   // stage Bs2: 192 rows x 4 segs = 768
            int f = tid + it * 256;
            int r = f >> 2, s = (f & 3) * 8;
            *(int4*)&Bs[r][s] = *(const int4*)&w2t[(long)r * K2P + k0 + s];
        }
        __syncthreads();
        f16x8 af0 = *(const f16x8*)&H1s[wm * 32 + lm][k0 + lq * 8];
        f16x8 af1 = *(const f16x8*)&H1s[wm * 32 + 16 + lm][k0 + lq * 8];
        #pragma unroll
        for (int ns = 0; ns < 6; ++ns) {
            f16x8 bf = *(const f16x8*)&Bs[wn * 96 + ns * 16 + lm][lq * 8];
            acc2[0][ns] = __builtin_amdgcn_mfma_f32_16x16x32_f16(af0, bf, acc2[0][ns], 0, 0, 0);
            acc2[1][ns] = __builtin_amdgcn_mfma_f32_16x16x32_f16(af1, bf, acc2[1][ns], 0, 0, 0);
        }
        __syncthreads();
    }
    #pragma unroll
    for (int ms = 0; ms < 2; ++ms)
        #pragma unroll
        for (int ns = 0; ns < 6; ++ns) {
            int col = wn * 96 + ns * 16 + lm;
            if (col < F2) {
                #pragma unroll
                for (int i = 0; i < 4; ++i) {
                    int r = row0 + wm * 32 + ms * 16 + lq * 4 + i;
                    T2[(long)r * F2 + col] = f16_bits(acc2[ms][ns][i]);
                }
            }
        }
}

// ---------------- agg layer 2: 2 nodes/wave, depth-8, CSR double-buffered ----------------
__global__ __launch_bounds__(256) void k_agg2(const ushort_t* __restrict__ T16,   // [MPAD][168]
                                              const int* __restrict__ off,
                                              const unsigned long long* __restrict__ csr,
                                              const float* __restrict__ dinv,
                                              const float* __restrict__ b2,
                                              ushort_t* __restrict__ out2) {      // [N][168]
    int w = (blockIdx.x * 256 + threadIdx.x) >> 6;
    int lane = threadIdx.x & 63;
    if (w >= N_NODES / 2) return;
    const int g = lane >> 5, sl = lane & 31;
    const int v = 2 * w + g;
    const bool act = sl < 21;                     // 21 lanes x 8 halves = 168
    int o0A = off[2 * w], oM = off[2 * w + 1], o1B = off[2 * w + 2];
    int o0 = g ? oM : o0A;
    int n  = g ? (o1B - oM) : (oM - o0A);
    int nmax = max(oM - o0A, o1B - oM);
    float di = dinv[v];
    float4 a0 = {0, 0, 0, 0}, a1 = {0, 0, 0, 0};
    if (act) {
        uint4 u = *(const uint4*)(T16 + (long)v * F2 + sl * 8);
        float2 f0 = __half22float2(*(__half2*)&u.x);
        float2 f1 = __half22float2(*(__half2*)&u.y);
        float2 f2 = __half22float2(*(__half2*)&u.z);
        float2 f3 = __half22float2(*(__half2*)&u.w);
        float s2 = di * di;
        a0.x = f0.x * s2; a0.y = f0.y * s2; a0.z = f1.x * s2; a0.w = f1.y * s2;
        a1.x = f2.x * s2; a1.y = f2.y * s2; a1.z = f3.x * s2; a1.w = f3.y * s2;
    }
    int nm1 = max(n - 1, 0);
    unsigned long long e[8];
    #pragma unroll
    for (int j = 0; j < 8; ++j)
        e[j] = csr[min(o0 + min(j, nm1), N_EDGES - 1)];   // prime
    for (int b = 0; b < nmax; b += 8) {
        unsigned long long en[8];
        #pragma unroll
        for (int j = 0; j < 8; ++j)                        // prefetch next iter's records
            en[j] = csr[min(o0 + min(b + 8 + j, nm1), N_EDGES - 1)];
        uint4 u[8];
        #pragma unroll
        for (int j = 0; j < 8; ++j) {
            int s = ((b + j) < n) ? (int)(unsigned)(e[j] & 0xFFFFFFFFu) : v;
            if (act) u[j] = *(const uint4*)(T16 + (long)s * F2 + sl * 8);
        }
        #pragma unroll
        for (int j = 0; j < 8; ++j) {
            float c = ((b + j) < n) ? __uint_as_float((unsigned)(e[j] >> 32)) : 0.0f;
            float2 f0 = __half22float2(*(__half2*)&u[j].x);
            float2 f1 = __half22float2(*(__half2*)&u[j].y);
            float2 f2 = __half22float2(*(__half2*)&u[j].z);
            float2 f3 = __half22float2(*(__half2*)&u[j].w);
            a0.x += c * f0.x; a0.y += c * f0.y; a0.z += c * f1.x; a0.w += c * f1.y;
            a1.x += c * f2.x; a1.y += c * f2.y; a1.z += c * f3.x; a1.w += c * f3.y;
        }
        #pragma unroll
        for (int j = 0; j < 8; ++j) e[j] = en[j];
    }
    if (act) {
        float4 bb0 = ((const float4*)b2)[sl * 2];
        float4 bb1 = ((const float4*)b2)[sl * 2 + 1];
        __half2 h0 = __floats2half2_rn(fmaxf(a0.x + bb0.x, 0.0f), fmaxf(a0.y + bb0.y, 0.0f));
        __half2 h1 = __floats2half2_rn(fmaxf(a0.z + bb0.z, 0.0f), fmaxf(a0.w + bb0.w, 0.0f));
        __half2 h2 = __floats2half2_rn(fmaxf(a1.x + bb1.x, 0.0f), fmaxf(a1.y + bb1.y, 0.0f));
        __half2 h3 = __floats2half2_rn(fmaxf(a1.z + bb1.z, 0.0f), fmaxf(a1.w + bb1.w, 0.0f));
        uint4 o;
        o.x = *(unsigned*)&h0; o.y = *(unsigned*)&h1;
        o.z = *(unsigned*)&h2; o.w = *(unsigned*)&h3;
        *(uint4*)(out2 + (long)v * F2 + sl * 8) = o;
    }
}

// ---------------- fused per-graph max pool + MLP head ----------------
__global__ __launch_bounds__(256) void k_pool_head(const ushort_t* __restrict__ out2,
        const int* __restrict__ r0, const int* __restrict__ r1,
        const float* __restrict__ Wg, const float* __restrict__ bg,
        const float* __restrict__ Wf, const float* __restrict__ bf,
        const float* __restrict__ Wo, const float* __restrict__ bo,
        float* __restrict__ out) {
    __shared__ float4 sm[4][F2 / 4];
    __shared__ float s0[F2];
    __shared__ float s1[84];
    __shared__ float s2[42];
    int gi = blockIdx.x;
    int slot = threadIdx.x >> 6, lane = threadIdx.x & 63;
    int a = r0[gi], b = r1[gi];
    if (lane < F2 / 4) {
        float4 mx = {0, 0, 0, 0};
        for (int v = a + slot; v < b; v += 4) {
            uint2 u = ((const uint2*)(out2 + (long)v * F2))[lane];
            float2 f0 = __half22float2(*(__half2*)&u.x);
            float2 f1 = __half22float2(*(__half2*)&u.y);
            mx.x = fmaxf(mx.x, f0.x); mx.y = fmaxf(mx.y, f0.y);
            mx.z = fmaxf(mx.z, f1.x); mx.w = fmaxf(mx.w, f1.y);
        }
        sm[slot][lane] = mx;
    }
    __syncthreads();
    if (slot == 0 && lane < F2 / 4) {
        float4 m0 = sm[0][lane], m1 = sm[1][lane], m2 = sm[2][lane], m3 = sm[3][lane];
        float4 r;
        r.x = fmaxf(fmaxf(m0.x, m1.x), fmaxf(m2.x, m3.x));
        r.y = fmaxf(fmaxf(m0.y, m1.y), fmaxf(m2.y, m3.y));
        r.z = fmaxf(fmaxf(m0.z, m1.z), fmaxf(m2.z, m3.z));
        r.w = fmaxf(fmaxf(m0.w, m1.w), fmaxf(m2.w, m3.w));
        ((float4*)s0)[lane] = r;
    }
    __syncthreads();
    int t = threadIdx.x;
    if (t < 84) {
        float acc = bg[t];
        #pragma unroll 4
        for (int k = 0; k < F2; ++k) acc += s0[k] * Wg[k * 84 + t];
        s1[t] = fmaxf(acc, 0.0f);
    }
    __syncthreads();
    if (t < 42) {
        float acc = bf[t];
        #pragma unroll 4
        for (int k = 0; k < 84; ++k) acc += s1[k] * Wf[k * 42 + t];
        s2[t] = fmaxf(acc, 0.0f);
    }
    __syncthreads();
    if (t == 0) {
        float acc = bo[0];
        for (int k = 0; k < 42; ++k) acc += s2[k] * Wo[k];
        out[gi] = acc;
    }
}

extern "C" void kernel_launch(void* const* d_in, const int* in_sizes, int n_in,
                              void* d_out, int out_size, void* d_ws, size_t ws_size,
                              hipStream_t stream) {
    const float* x   = (const float*)d_in[0];
    const int*   ei  = (const int*)d_in[1];
    const int*   bat = (const int*)d_in[2];
    const float* W1  = (const float*)d_in[3];
    const float* b1  = (const float*)d_in[4];
    const float* W2  = (const float*)d_in[5];
    const float* b2  = (const float*)d_in[6];
    const float* Wg  = (const float*)d_in[7];
    const float* bg  = (const float*)d_in[8];
    const float* Wf  = (const float*)d_in[9];
    const float* bf  = (const float*)d_in[10];
    const float* Wo  = (const float*)d_in[11];
    const float* bo  = (const float*)d_in[12];
    float* out = (float*)d_out;

    // ---- workspace carve-up (16B-aligned chunks; dcount+cur adjacent) ----
    char* p = (char*)d_ws;
    float* dinv     = (float*)p; p += 50048 * 4;
    int*   dcount   = (int*)p;   p += 50048 * 4;
    int*   cur      = (int*)p;   p += 50048 * 4;
    int*   off      = (int*)p;   p += 50064 * 4;
    int*   partials = (int*)p;   p += 64 * 4;
    int*   rng0     = (int*)p;   p += 256 * 4;
    int*   rng1     = (int*)p;   p += 256 * 4;
    unsigned long long* csr = (unsigned long long*)p; p += (long)N_EDGES * 8;
    ushort_t* x16   = (ushort_t*)p; p += (long)N_NODES * K1P * 2;   // padded 128
    ushort_t* aX    = (ushort_t*)p; p += (long)MPAD * K1P * 2;
    ushort_t* w1t   = (ushort_t*)p; p += (long)384 * K1P * 2;
    ushort_t* w2t   = (ushort_t*)p; p += (long)192 * K2P * 2;
    ushort_t* t16   = (ushort_t*)p; p += (long)MPAD * F2 * 2;       // unpadded 168
    ushort_t* o16   = (ushort_t*)p; p += (long)N_NODES * F2 * 2;

    const int* src = ei;
    const int* dst = ei + N_EDGES;
    const int B = 256;

    // ---- preproc ----
    k_zero_int<<<(2 * 50048 + B - 1) / B, B, 0, stream>>>(dcount, 2 * 50048);
    k_prep<<<PREP_BLOCKS, B, 0, stream>>>(x, dst, W1, W2, bat, x16, dcount, w1t, w2t, rng0, rng1);
    k_scan1<<<SCAN_BLOCKS, SCAN_CHUNK, 0, stream>>>(dcount, off, partials, dinv, N_NODES);
    k_scan3<<<SCAN_BLOCKS, SCAN_CHUNK, 0, stream>>>(off, partials, N_NODES);
    k_scatter<<<(N_EDGES / 2 + B - 1) / B, B, 0, stream>>>(src, dst, off, cur, dinv, csr, N_EDGES / 2);

    // ---- layer 1 agg + fused GEMM1/GEMM2 ----
    k_agg1<<<(N_NODES / 2 * 64) / 256, 256, 0, stream>>>(x16, off, csr, dinv, aX);
    k_gemm_fused<<<MPAD / 64, 256, 0, stream>>>(aX, w1t, b1, w2t, t16);

    // ---- layer 2 agg ----
    k_agg2<<<(N_NODES / 2 * 64) / 256, 256, 0, stream>>>(t16, off, csr, dinv, b2, o16);

    // ---- pool + head fused ----
    k_pool_head<<<NGRAPH, 256, 0, stream>>>(o16, rng0, rng1, Wg, bg, Wf, bf, Wo, bo, out);
}

// Round 14
// 281.038 us; speedup vs baseline: 1.0348x; 1.0348x over previous
//
#include <hip/hip_runtime.h>
#include <hip/hip_fp16.h>

#define N_NODES 50000
#define MPAD    50048            // 782 * 64
#define N_EDGES 500000
#define F_IN    112
#define K1P     128              // F_IN padded (halves per x16/aX row)
#define F1      336
#define K2P     352              // F1 padded to 32-multiple
#define F2      168
#define NGRAPH  256
#define SCAN_CHUNK 1024
#define SCAN_BLOCKS ((N_NODES + SCAN_CHUNK - 1) / SCAN_CHUNK)   // 49

typedef __attribute__((ext_vector_type(8))) _Float16 f16x8;
typedef __attribute__((ext_vector_type(4))) float f32x4;
typedef unsigned short ushort_t;
typedef unsigned long long u64_t;

__device__ __forceinline__ ushort_t f16_bits(float x) {
    __half h = __float2half_rn(x);
    return *(ushort_t*)&h;
}

// ---------------- small utility kernels ----------------
__global__ void k_zero_int(int* p, int n) {
    int i = blockIdx.x * blockDim.x + threadIdx.x;
    if (i < n) p[i] = 0;
}

// ---------------- fused prep: cvtX(pad128) | count_deg | cvtW1 | cvtW2 | ranges ----------------
#define CVX_BLOCKS  ((N_NODES * 32) / 256)                 // 6250 (uint2 per thread)
#define CNT_BLOCKS  ((N_EDGES / 2 + 255) / 256)            // 977
#define CVW1_BLOCKS ((384 * K1P + 255) / 256)              // 192
#define CVW2_BLOCKS ((192 * K2P + 255) / 256)              // 264
#define RNG_BLOCKS  ((N_NODES + 255) / 256)                // 196
#define PREP_BLOCKS (CVX_BLOCKS + CNT_BLOCKS + CVW1_BLOCKS + CVW2_BLOCKS + RNG_BLOCKS)

__global__ __launch_bounds__(256) void k_prep(const float* __restrict__ x,
                                              const int* __restrict__ dst,
                                              const float* __restrict__ W1,
                                              const float* __restrict__ W2,
                                              const int* __restrict__ batch,
                                              ushort_t* __restrict__ x16,   // [N][128]
                                              int* __restrict__ dcount,
                                              ushort_t* __restrict__ w1t,   // [384][128]
                                              ushort_t* __restrict__ w2t,   // [192][352]
                                              int* __restrict__ r0, int* __restrict__ r1) {
    int bid = blockIdx.x;
    int t = threadIdx.x;
    if (bid < CVX_BLOCKS) {                       // X fp32 -> fp16, padded rows of 128 halves
        int i = bid * 256 + t;                    // uint2 (4 halves) index; i = v*32 + c
        int v = i >> 5, c = i & 31;
        uint2 u = {0, 0};
        if (c < 28) {
            float4 f = *(const float4*)&x[(long)v * F_IN + c * 4];
            __half2 h0 = __floats2half2_rn(f.x, f.y);
            __half2 h1 = __floats2half2_rn(f.z, f.w);
            u.x = *(unsigned*)&h0; u.y = *(unsigned*)&h1;
        }
        ((uint2*)x16)[i] = u;
        return;
    }
    bid -= CVX_BLOCKS;
    if (bid < CNT_BLOCKS) {                       // degree count, 2 edges/thread
        int i = bid * 256 + t;
        if (i < N_EDGES / 2) {
            int2 d = ((const int2*)dst)[i];
            atomicAdd(&dcount[d.x], 1);
            atomicAdd(&dcount[d.y], 1);
        }
        return;
    }
    bid -= CNT_BLOCKS;
    if (bid < CVW1_BLOCKS) {                      // W1[K,N] -> w1t[n][k]
        int idx = bid * 256 + t;
        if (idx < 384 * K1P) {
            int n = idx / K1P, k = idx % K1P;
            float v = (n < F1 && k < F_IN) ? W1[k * F1 + n] : 0.0f;
            w1t[idx] = f16_bits(v);
        }
        return;
    }
    bid -= CVW1_BLOCKS;
    if (bid < CVW2_BLOCKS) {                      // W2[K,N] -> w2t[n][k]
        int idx = bid * 256 + t;
        if (idx < 192 * K2P) {
            int n = idx / K2P, k = idx % K2P;
            float v = (n < F2 && k < F1) ? W2[k * F2 + n] : 0.0f;
            w2t[idx] = f16_bits(v);
        }
        return;
    }
    bid -= CVW2_BLOCKS;
    {                                             // per-graph ranges (batch sorted)
        int v = bid * 256 + t;
        if (v >= N_NODES) return;
        int b = batch[v];
        if (v == 0 || batch[v - 1] != b) r0[b] = v;
        if (v == N_NODES - 1 || batch[v + 1] != b) r1[b] = v + 1;
    }
}

// ---------------- scan pass 1 (dinv fused) ----------------
__global__ __launch_bounds__(SCAN_CHUNK) void k_scan1(const int* __restrict__ dcount,
                                                      int* __restrict__ off,
                                                      int* __restrict__ partials,
                                                      float* __restrict__ dinv, int n) {
    __shared__ int s[SCAN_CHUNK];
    int t = threadIdx.x;
    int i = blockIdx.x * SCAN_CHUNK + t;
    int val = (i < n) ? dcount[i] : 0;
    s[t] = val;
    __syncthreads();
    for (int d = 1; d < SCAN_CHUNK; d <<= 1) {
        int x = (t >= d) ? s[t - d] : 0;
        __syncthreads();
        s[t] += x;
        __syncthreads();
    }
    if (i < n) {
        off[i] = s[t] - val;
        dinv[i] = rsqrtf((float)val + 1.0f);      // +1 self-loop
    }
    if (t == SCAN_CHUNK - 1) partials[blockIdx.x] = s[t];
}
// scan pass 2+3 merged
__global__ __launch_bounds__(SCAN_CHUNK) void k_scan3(int* __restrict__ off,
                                                      const int* __restrict__ partials, int n) {
    __shared__ int tmp[SCAN_BLOCKS];
    __shared__ int pref[SCAN_BLOCKS];
    int t = threadIdx.x;
    if (t < SCAN_BLOCKS) tmp[t] = partials[t];
    __syncthreads();
    if (t == 0) {
        int run = 0;
        for (int j = 0; j < SCAN_BLOCKS; ++j) { pref[j] = run; run += tmp[j]; }
    }
    __syncthreads();
    int i = blockIdx.x * SCAN_CHUNK + t;
    if (i < n) off[i] += pref[blockIdx.x];
    if (i == n) off[i] = N_EDGES;
}

// ---------------- scatter edges into dst-sorted CSR, 2 edges/thread ----------------
__global__ void k_scatter(const int* __restrict__ src, const int* __restrict__ dst,
                          const int* __restrict__ off, int* __restrict__ cur,
                          const float* __restrict__ dinv,
                          u64_t* __restrict__ csr, int e2) {
    int i = blockIdx.x * blockDim.x + threadIdx.x;
    if (i >= e2) return;
    int2 s2 = ((const int2*)src)[i];
    int2 d2 = ((const int2*)dst)[i];
    {
        int pos = atomicAdd(&cur[d2.x], 1);
        unsigned coef = __float_as_uint(dinv[s2.x] * dinv[d2.x]);
        u64_t rec = (unsigned)s2.x | ((u64_t)coef << 32);
        __builtin_nontemporal_store(rec, &csr[off[d2.x] + pos]);
    }
    {
        int pos = atomicAdd(&cur[d2.y], 1);
        unsigned coef = __float_as_uint(dinv[s2.y] * dinv[d2.y]);
        u64_t rec = (unsigned)s2.y | ((u64_t)coef << 32);
        __builtin_nontemporal_store(rec, &csr[off[d2.y] + pos]);
    }
}

// ---------------- agg layer 1: 2 nodes/wave, depth-8 (r11-best config) ----------------
__global__ __launch_bounds__(256) void k_agg1(const ushort_t* __restrict__ X16,
                                              const int* __restrict__ off,
                                              const u64_t* __restrict__ csr,
                                              const float* __restrict__ dinv,
                                              ushort_t* __restrict__ aX) {
    int w = (blockIdx.x * 256 + threadIdx.x) >> 6;
    int lane = threadIdx.x & 63;
    if (w >= N_NODES / 2) return;
    const int g = lane >> 5, sl = lane & 31;
    const int v = 2 * w + g;
    int o0A = off[2 * w], oM = off[2 * w + 1], o1B = off[2 * w + 2];
    int o0 = g ? oM : o0A;
    int n  = g ? (o1B - oM) : (oM - o0A);
    int nmax = max(oM - o0A, o1B - oM);
    float di = dinv[v];
    float s2 = di * di;
    // all 32 lanes live: pad cols are zero in X16
    uint2 us = *(const uint2*)(X16 + (long)v * K1P + sl * 4);
    float2 sf0 = __half22float2(*(__half2*)&us.x);
    float2 sf1 = __half22float2(*(__half2*)&us.y);
    float4 acc = {sf0.x * s2, sf0.y * s2, sf1.x * s2, sf1.y * s2};
    int nm1 = max(n - 1, 0);
    for (int b = 0; b < nmax; b += 8) {
        u64_t e[8];
        #pragma unroll
        for (int j = 0; j < 8; ++j) {
            int cidx = min(o0 + min(b + j, nm1), N_EDGES - 1);
            e[j] = csr[cidx];                     // uniform per half-wave -> broadcast
        }
        uint2 u[8];
        #pragma unroll
        for (int j = 0; j < 8; ++j)
            u[j] = *(const uint2*)(X16 + (long)(unsigned)(e[j] & 0xFFFFFFFFu) * K1P + sl * 4);
        #pragma unroll
        for (int j = 0; j < 8; ++j) {
            float c = ((b + j) < n) ? __uint_as_float((unsigned)(e[j] >> 32)) : 0.0f;
            float2 f0 = __half22float2(*(__half2*)&u[j].x);
            float2 f1 = __half22float2(*(__half2*)&u[j].y);
            acc.x += c * f0.x; acc.y += c * f0.y; acc.z += c * f1.x; acc.w += c * f1.y;
        }
    }
    __half2 h0 = __floats2half2_rn(acc.x, acc.y);
    __half2 h1 = __floats2half2_rn(acc.z, acc.w);
    uint2 o; o.x = *(unsigned*)&h0; o.y = *(unsigned*)&h1;
    *(uint2*)(aX + (long)v * K1P + sl * 4) = o;
}

// ---------------- fused GEMM1+GEMM2: T2 = (relu(aX@W1t^T + b1)) @ W2t^T ----------------
// One 64-row block: phase1 -> H1 tile (64x352 fp16) in LDS -> phase2 -> T2 (width 168, unpadded).
__global__ __launch_bounds__(256) void k_gemm_fused(
        const ushort_t* __restrict__ aX,    // [MPAD][128]
        const ushort_t* __restrict__ w1t,   // [384][128] rows 0..351 used
        const float* __restrict__ b1,       // [336]
        const ushort_t* __restrict__ w2t,   // [192][352]
        ushort_t* __restrict__ T2) {        // [MPAD][168]
    __shared__ ushort_t As[64][40];
    __shared__ ushort_t Bs[352][40];
    __shared__ ushort_t H1s[64][360];
    const int tid = threadIdx.x;
    const int row0 = blockIdx.x * 64;
    const int w = tid >> 6, l = tid & 63;
    const int wm = w >> 1, wn = w & 1;
    const int lm = l & 15, lq = l >> 4;

    // ---- phase 1 ----
    f32x4 acc1[2][11];
    #pragma unroll
    for (int i = 0; i < 2; ++i)
        #pragma unroll
        for (int j = 0; j < 11; ++j) acc1[i][j] = (f32x4){0.f, 0.f, 0.f, 0.f};

    for (int k0 = 0; k0 < K1P; k0 += 32) {
        {   // stage As
            int r = tid >> 2, s = (tid & 3) * 8;
            *(int4*)&As[r][s] = *(const int4*)&aX[(long)(row0 + r) * K1P + k0 + s];
        }
        #pragma unroll
        for (int it = 0; it < 6; ++it) {   // stage Bs: 352 rows x 4 segs = 1408
            int f = tid + it * 256;
            if (f < 1408) {
                int r = f >> 2, s = (f & 3) * 8;
                *(int4*)&Bs[r][s] = *(const int4*)&w1t[(long)r * K1P + k0 + s];
            }
        }
        __syncthreads();
        f16x8 af0 = *(const f16x8*)&As[wm * 32 + lm][lq * 8];
        f16x8 af1 = *(const f16x8*)&As[wm * 32 + 16 + lm][lq * 8];
        #pragma unroll
        for (int ns = 0; ns < 11; ++ns) {
            f16x8 bf = *(const f16x8*)&Bs[wn * 176 + ns * 16 + lm][lq * 8];
            acc1[0][ns] = __builtin_amdgcn_mfma_f32_16x16x32_f16(af0, bf, acc1[0][ns], 0, 0, 0);
            acc1[1][ns] = __builtin_amdgcn_mfma_f32_16x16x32_f16(af1, bf, acc1[1][ns], 0, 0, 0);
        }
        __syncthreads();
    }
    // write H1 tile to LDS with bias+relu (C/D layout: col=lm, row=lq*4+i)
    #pragma unroll
    for (int ms = 0; ms < 2; ++ms)
        #pragma unroll
        for (int ns = 0; ns < 11; ++ns) {
            int col = wn * 176 + ns * 16 + lm;
            float bb = (col < F1) ? b1[col] : 0.0f;
            #pragma unroll
            for (int i = 0; i < 4; ++i) {
                int r = wm * 32 + ms * 16 + lq * 4 + i;
                H1s[r][col] = f16_bits(fmaxf(acc1[ms][ns][i] + bb, 0.0f));
            }
        }
    __syncthreads();

    // ---- phase 2 ----
    f32x4 acc2[2][6];
    #pragma unroll
    for (int i = 0; i < 2; ++i)
        #pragma unroll
        for (int j = 0; j < 6; ++j) acc2[i][j] = (f32x4){0.f, 0.f, 0.f, 0.f};

    for (int k0 = 0; k0 < K2P; k0 += 32) {
        #pragma unroll
        for (int it = 0; it < 3; ++it) {   // stage Bs2: 192 rows x 4 segs = 768
            int f = tid + it * 256;
            int r = f >> 2, s = (f & 3) * 8;
            *(int4*)&Bs[r][s] = *(const int4*)&w2t[(long)r * K2P + k0 + s];
        }
        __syncthreads();
        f16x8 af0 = *(const f16x8*)&H1s[wm * 32 + lm][k0 + lq * 8];
        f16x8 af1 = *(const f16x8*)&H1s[wm * 32 + 16 + lm][k0 + lq * 8];
        #pragma unroll
        for (int ns = 0; ns < 6; ++ns) {
            f16x8 bf = *(const f16x8*)&Bs[wn * 96 + ns * 16 + lm][lq * 8];
            acc2[0][ns] = __builtin_amdgcn_mfma_f32_16x16x32_f16(af0, bf, acc2[0][ns], 0, 0, 0);
            acc2[1][ns] = __builtin_amdgcn_mfma_f32_16x16x32_f16(af1, bf, acc2[1][ns], 0, 0, 0);
        }
        __syncthreads();
    }
    #pragma unroll
    for (int ms = 0; ms < 2; ++ms)
        #pragma unroll
        for (int ns = 0; ns < 6; ++ns) {
            int col = wn * 96 + ns * 16 + lm;
            if (col < F2) {
                #pragma unroll
                for (int i = 0; i < 4; ++i) {
                    int r = row0 + wm * 32 + ms * 16 + lq * 4 + i;
                    T2[(long)r * F2 + col] = f16_bits(acc2[ms][ns][i]);
                }
            }
        }
}

// ---------------- agg layer 2: 2 nodes/wave, depth-8 (r11-best config) ----------------
__global__ __launch_bounds__(256) void k_agg2(const ushort_t* __restrict__ T16,   // [MPAD][168]
                                              const int* __restrict__ off,
                                              const u64_t* __restrict__ csr,
                                              const float* __restrict__ dinv,
                                              const float* __restrict__ b2,
                                              ushort_t* __restrict__ out2) {      // [N][168]
    int w = (blockIdx.x * 256 + threadIdx.x) >> 6;
    int lane = threadIdx.x & 63;
    if (w >= N_NODES / 2) return;
    const int g = lane >> 5, sl = lane & 31;
    const int v = 2 * w + g;
    const bool act = sl < 21;                     // 21 lanes x 8 halves = 168
    int o0A = off[2 * w], oM = off[2 * w + 1], o1B = off[2 * w + 2];
    int o0 = g ? oM : o0A;
    int n  = g ? (o1B - oM) : (oM - o0A);
    int nmax = max(oM - o0A, o1B - oM);
    float di = dinv[v];
    float4 a0 = {0, 0, 0, 0}, a1 = {0, 0, 0, 0};
    if (act) {
        uint4 u = *(const uint4*)(T16 + (long)v * F2 + sl * 8);
        float2 f0 = __half22float2(*(__half2*)&u.x);
        float2 f1 = __half22float2(*(__half2*)&u.y);
        float2 f2 = __half22float2(*(__half2*)&u.z);
        float2 f3 = __half22float2(*(__half2*)&u.w);
        float s2 = di * di;
        a0.x = f0.x * s2; a0.y = f0.y * s2; a0.z = f1.x * s2; a0.w = f1.y * s2;
        a1.x = f2.x * s2; a1.y = f2.y * s2; a1.z = f3.x * s2; a1.w = f3.y * s2;
    }
    int nm1 = max(n - 1, 0);
    for (int b = 0; b < nmax; b += 8) {
        u64_t e[8];
        #pragma unroll
        for (int j = 0; j < 8; ++j) {
            int cidx = min(o0 + min(b + j, nm1), N_EDGES - 1);
            e[j] = csr[cidx];
        }
        uint4 u[8];
        #pragma unroll
        for (int j = 0; j < 8; ++j) {
            int s = ((b + j) < n) ? (int)(unsigned)(e[j] & 0xFFFFFFFFu) : v;
            if (act) u[j] = *(const uint4*)(T16 + (long)s * F2 + sl * 8);
        }
        #pragma unroll
        for (int j = 0; j < 8; ++j) {
            float c = ((b + j) < n) ? __uint_as_float((unsigned)(e[j] >> 32)) : 0.0f;
            float2 f0 = __half22float2(*(__half2*)&u[j].x);
            float2 f1 = __half22float2(*(__half2*)&u[j].y);
            float2 f2 = __half22float2(*(__half2*)&u[j].z);
            float2 f3 = __half22float2(*(__half2*)&u[j].w);
            a0.x += c * f0.x; a0.y += c * f0.y; a0.z += c * f1.x; a0.w += c * f1.y;
            a1.x += c * f2.x; a1.y += c * f2.y; a1.z += c * f3.x; a1.w += c * f3.y;
        }
    }
    if (act) {
        float4 bb0 = ((const float4*)b2)[sl * 2];
        float4 bb1 = ((const float4*)b2)[sl * 2 + 1];
        __half2 h0 = __floats2half2_rn(fmaxf(a0.x + bb0.x, 0.0f), fmaxf(a0.y + bb0.y, 0.0f));
        __half2 h1 = __floats2half2_rn(fmaxf(a0.z + bb0.z, 0.0f), fmaxf(a0.w + bb0.w, 0.0f));
        __half2 h2 = __floats2half2_rn(fmaxf(a1.x + bb1.x, 0.0f), fmaxf(a1.y + bb1.y, 0.0f));
        __half2 h3 = __floats2half2_rn(fmaxf(a1.z + bb1.z, 0.0f), fmaxf(a1.w + bb1.w, 0.0f));
        uint4 o;
        o.x = *(unsigned*)&h0; o.y = *(unsigned*)&h1;
        o.z = *(unsigned*)&h2; o.w = *(unsigned*)&h3;
        *(uint4*)(out2 + (long)v * F2 + sl * 8) = o;
    }
}

// ---------------- fused per-graph max pool + MLP head ----------------
__global__ __launch_bounds__(256) void k_pool_head(const ushort_t* __restrict__ out2,
        const int* __restrict__ r0, const int* __restrict__ r1,
        const float* __restrict__ Wg, const float* __restrict__ bg,
        const float* __restrict__ Wf, const float* __restrict__ bf,
        const float* __restrict__ Wo, const float* __restrict__ bo,
        float* __restrict__ out) {
    __shared__ float4 sm[4][F2 / 4];
    __shared__ float s0[F2];
    __shared__ float s1[84];
    __shared__ float s2[42];
    int gi = blockIdx.x;
    int slot = threadIdx.x >> 6, lane = threadIdx.x & 63;
    int a = r0[gi], b = r1[gi];
    if (lane < F2 / 4) {
        float4 mx = {0, 0, 0, 0};
        for (int v = a + slot; v < b; v += 4) {
            uint2 u = ((const uint2*)(out2 + (long)v * F2))[lane];
            float2 f0 = __half22float2(*(__half2*)&u.x);
            float2 f1 = __half22float2(*(__half2*)&u.y);
            mx.x = fmaxf(mx.x, f0.x); mx.y = fmaxf(mx.y, f0.y);
            mx.z = fmaxf(mx.z, f1.x); mx.w = fmaxf(mx.w, f1.y);
        }
        sm[slot][lane] = mx;
    }
    __syncthreads();
    if (slot == 0 && lane < F2 / 4) {
        float4 m0 = sm[0][lane], m1 = sm[1][lane], m2 = sm[2][lane], m3 = sm[3][lane];
        float4 r;
        r.x = fmaxf(fmaxf(m0.x, m1.x), fmaxf(m2.x, m3.x));
        r.y = fmaxf(fmaxf(m0.y, m1.y), fmaxf(m2.y, m3.y));
        r.z = fmaxf(fmaxf(m0.z, m1.z), fmaxf(m2.z, m3.z));
        r.w = fmaxf(fmaxf(m0.w, m1.w), fmaxf(m2.w, m3.w));
        ((float4*)s0)[lane] = r;
    }
    __syncthreads();
    int t = threadIdx.x;
    if (t < 84) {
        float acc = bg[t];
        #pragma unroll 4
        for (int k = 0; k < F2; ++k) acc += s0[k] * Wg[k * 84 + t];
        s1[t] = fmaxf(acc, 0.0f);
    }
    __syncthreads();
    if (t < 42) {
        float acc = bf[t];
        #pragma unroll 4
        for (int k = 0; k < 84; ++k) acc += s1[k] * Wf[k * 42 + t];
        s2[t] = fmaxf(acc, 0.0f);
    }
    __syncthreads();
    if (t == 0) {
        float acc = bo[0];
        for (int k = 0; k < 42; ++k) acc += s2[k] * Wo[k];
        out[gi] = acc;
    }
}

extern "C" void kernel_launch(void* const* d_in, const int* in_sizes, int n_in,
                              void* d_out, int out_size, void* d_ws, size_t ws_size,
                              hipStream_t stream) {
    const float* x   = (const float*)d_in[0];
    const int*   ei  = (const int*)d_in[1];
    const int*   bat = (const int*)d_in[2];
    const float* W1  = (const float*)d_in[3];
    const float* b1  = (const float*)d_in[4];
    const float* W2  = (const float*)d_in[5];
    const float* b2  = (const float*)d_in[6];
    const float* Wg  = (const float*)d_in[7];
    const float* bg  = (const float*)d_in[8];
    const float* Wf  = (const float*)d_in[9];
    const float* bf  = (const float*)d_in[10];
    const float* Wo  = (const float*)d_in[11];
    const float* bo  = (const float*)d_in[12];
    float* out = (float*)d_out;

    // ---- workspace carve-up (16B-aligned chunks; dcount+cur adjacent) ----
    char* p = (char*)d_ws;
    float* dinv     = (float*)p; p += 50048 * 4;
    int*   dcount   = (int*)p;   p += 50048 * 4;
    int*   cur      = (int*)p;   p += 50048 * 4;
    int*   off      = (int*)p;   p += 50064 * 4;
    int*   partials = (int*)p;   p += 64 * 4;
    int*   rng0     = (int*)p;   p += 256 * 4;
    int*   rng1     = (int*)p;   p += 256 * 4;
    u64_t* csr      = (u64_t*)p; p += (long)N_EDGES * 8;
    ushort_t* x16   = (ushort_t*)p; p += (long)N_NODES * K1P * 2;   // padded 128
    ushort_t* aX    = (ushort_t*)p; p += (long)MPAD * K1P * 2;
    ushort_t* w1t   = (ushort_t*)p; p += (long)384 * K1P * 2;
    ushort_t* w2t   = (ushort_t*)p; p += (long)192 * K2P * 2;
    ushort_t* t16   = (ushort_t*)p; p += (long)MPAD * F2 * 2;       // unpadded 168
    ushort_t* o16   = (ushort_t*)p; p += (long)N_NODES * F2 * 2;

    const int* src = ei;
    const int* dst = ei + N_EDGES;
    const int B = 256;

    // ---- preproc ----
    k_zero_int<<<(2 * 50048 + B - 1) / B, B, 0, stream>>>(dcount, 2 * 50048);
    k_prep<<<PREP_BLOCKS, B, 0, stream>>>(x, dst, W1, W2, bat, x16, dcount, w1t, w2t, rng0, rng1);
    k_scan1<<<SCAN_BLOCKS, SCAN_CHUNK, 0, stream>>>(dcount, off, partials, dinv, N_NODES);
    k_scan3<<<SCAN_BLOCKS, SCAN_CHUNK, 0, stream>>>(off, partials, N_NODES);
    k_scatter<<<(N_EDGES / 2 + B - 1) / B, B, 0, stream>>>(src, dst, off, cur, dinv, csr, N_EDGES / 2);

    // ---- layer 1 agg + fused GEMM1/GEMM2 ----
    k_agg1<<<(N_NODES / 2 * 64) / 256, 256, 0, stream>>>(x16, off, csr, dinv, aX);
    k_gemm_fused<<<MPAD / 64, 256, 0, stream>>>(aX, w1t, b1, w2t, t16);

    // ---- layer 2 agg ----
    k_agg2<<<(N_NODES / 2 * 64) / 256, 256, 0, stream>>>(t16, off, csr, dinv, b2, o16);

    // ---- pool + head fused ----
    k_pool_head<<<NGRAPH, 256, 0, stream>>>(o16, rng0, rng1, Wg, bg, Wf, bf, Wo, bo, out);
}